// Round 3
// baseline (1176.180 us; speedup 1.0000x reference)
//
#include <hip/hip_runtime.h>
#include <hip/hip_bf16.h>

typedef __attribute__((ext_vector_type(8))) short short8;
typedef __attribute__((ext_vector_type(4))) float f32x4;
typedef unsigned int uint;

#define T_TOK 8192
#define D_DIM 1024
#define F_DIM 4096
#define E_NUM 8
#define KTOP 2

// ---------------------------------------------------------------------------
// Chunked bijective XCD swizzle (nwg % 8 == 0): consecutive post-swizzle ids
// land on the SAME XCD.
// ---------------------------------------------------------------------------
__device__ __forceinline__ int xcd_swizzle(int bid, int nwg) {
    return (bid & 7) * (nwg >> 3) + (bid >> 3);
}

__device__ __forceinline__ short bf16bits(float v) {
    __hip_bfloat16 h = __float2bfloat16(v);
    return *reinterpret_cast<short*>(&h);
}

// ---------------------------------------------------------------------------
// fp32 -> bf16 convert (weights)
// ---------------------------------------------------------------------------
__global__ void cvt_kernel(const float* __restrict__ in, short* __restrict__ out, int n8) {
    int i = blockIdx.x * blockDim.x + threadIdx.x;
    int stride = gridDim.x * blockDim.x;
    for (; i < n8; i += stride) {
        const float4* p = (const float4*)(in + (size_t)i * 8);
        float4 a = p[0], b = p[1];
        float va[8] = {a.x, a.y, a.z, a.w, b.x, b.y, b.z, b.w};
        short8 o;
#pragma unroll
        for (int j = 0; j < 8; ++j) o[j] = bf16bits(va[j]);
        *(short8*)(out + (size_t)i * 8) = o;
    }
}

// ---------------------------------------------------------------------------
// Gate: logits, softmax->probs, top-2, counts. Also converts x -> bf16 (fused).
// One wave per token.
// ---------------------------------------------------------------------------
__global__ void gate_kernel(const float* __restrict__ x, const float* __restrict__ gw,
                            float* __restrict__ probs, int4* __restrict__ idxrank,
                            float2* __restrict__ ww, int* __restrict__ counts,
                            short* __restrict__ xb) {
    const int lane = threadIdx.x & 63;
    const int wid = threadIdx.x >> 6;
    const int t = blockIdx.x * 4 + wid;
    const float4* xr = (const float4*)(x + (size_t)t * D_DIM);
    float acc[E_NUM];
#pragma unroll
    for (int e = 0; e < E_NUM; ++e) acc[e] = 0.f;
    for (int i = lane; i < D_DIM / 4; i += 64) {
        float4 xv = xr[i];
        // fused bf16 conversion of x
        short4 s;
        s.x = bf16bits(xv.x); s.y = bf16bits(xv.y);
        s.z = bf16bits(xv.z); s.w = bf16bits(xv.w);
        *(short4*)(xb + (size_t)t * D_DIM + i * 4) = s;
#pragma unroll
        for (int e = 0; e < E_NUM; ++e) {
            float4 gv = ((const float4*)(gw + (size_t)e * D_DIM))[i];
            acc[e] += xv.x * gv.x + xv.y * gv.y + xv.z * gv.z + xv.w * gv.w;
        }
    }
#pragma unroll
    for (int e = 0; e < E_NUM; ++e) {
#pragma unroll
        for (int off = 32; off > 0; off >>= 1) acc[e] += __shfl_xor(acc[e], off);
    }
    if (lane == 0) {
        float m = acc[0];
        for (int e = 1; e < E_NUM; ++e) m = fmaxf(m, acc[e]);
        float p[E_NUM], s = 0.f;
        for (int e = 0; e < E_NUM; ++e) { p[e] = expf(acc[e] - m); s += p[e]; }
        float inv = 1.f / s;
        for (int e = 0; e < E_NUM; ++e) {
            p[e] *= inv;
            probs[(size_t)t * E_NUM + e] = p[e];
        }
        float v0 = -1.f, v1 = -1.f; int i0 = 0, i1 = 0;
        for (int e = 0; e < E_NUM; ++e) {
            float v = p[e];
            if (v > v0) { v1 = v0; i1 = i0; v0 = v; i0 = e; }
            else if (v > v1) { v1 = v; i1 = e; }
        }
        float wsum = v0 + v1 + 1e-9f;
        int r0 = atomicAdd(&counts[i0], 1);
        int r1 = atomicAdd(&counts[i1], 1);
        idxrank[t] = make_int4(i0, i1, r0, r1);
        ww[t] = make_float2(v0 / wsum, v1 / wsum);
    }
}

__global__ void scan_kernel(const int* __restrict__ counts, int* __restrict__ offs) {
    if (threadIdx.x == 0 && blockIdx.x == 0) {
        int a = 0;
        for (int e = 0; e < E_NUM; ++e) { offs[e] = a; a += counts[e]; }
        offs[E_NUM] = a;
    }
}

__global__ void scatter_kernel(const int4* __restrict__ idxrank, const float2* __restrict__ ww,
                               const int* __restrict__ offs, int* __restrict__ token_list,
                               float* __restrict__ slot_w) {
    int t = blockIdx.x * blockDim.x + threadIdx.x;
    if (t >= T_TOK) return;
    int4 ir = idxrank[t];
    float2 w = ww[t];
    int s0 = offs[ir.x] + ir.z;
    int s1 = offs[ir.y] + ir.w;
    token_list[s0] = t; slot_w[s0] = w.x;
    token_list[s1] = t; slot_w[s1] = w.y;
}

// ---------------------------------------------------------------------------
// global -> LDS direct (16B per lane)
// ---------------------------------------------------------------------------
__device__ __forceinline__ void gload16(const void* g, void* l) {
    __builtin_amdgcn_global_load_lds((const __attribute__((address_space(1))) uint*)g,
                                     (__attribute__((address_space(3))) uint*)l, 16, 0, 0);
}

#define SBAR() __builtin_amdgcn_s_barrier()
#define SCHEDB() __builtin_amdgcn_sched_barrier(0)
#define WAITV4() asm volatile("s_waitcnt vmcnt(4)" ::: "memory")
#define WAITV0() asm volatile("s_waitcnt vmcnt(0)" ::: "memory")

// ===========================================================================
// 256x256 tile, BK=32, 4-buffer LDS ring, counted-vmcnt pipeline (T3+T4),
// conflict-free k-major LDS subtiles, setprio around MFMA (T5).
// 512 threads = 8 waves (2M x 4N); per-wave output 128x64 (8x4 frags).
//
// LDS chunk layout: lds[ring][op][fk*256+row][8 bf16]; staged via linear
// gload_lds dest + permuted per-lane SOURCE (m173). Frag ds_read_b128 at
// addr (fk4*256+row)*16 sweeps banks uniformly (8 dword-accesses/bank).
//
// Pipeline: stage K-tile t+2 while computing t.  Per-thread 4 loads/K-tile.
// End-of-t wait: tile t+1's loads were issued during t-1; younger = tile
// t+2's 4 -> vmcnt(4) (or 0 when t+2 doesn't exist). Raw s_barrier only —
// never __syncthreads (would drain vmcnt to 0). sched_barrier(0) pins the
// next K-tile's ds_reads behind the wait.
// ===========================================================================

// Per K-tile t: stage op-tile of K-tile t into ring slot t&3.
// Each thread covers chunks (half, row_s) and (half+2, row_s).
#define STAGE(op, ptr, t)                                                     \
    do {                                                                      \
        short* d_ = &lds[(t) & 3][op][half * 256 + row_s][0];                 \
        const short* s_ = (ptr) + (t) * 32;                                   \
        gload16(s_, d_);                                                      \
        gload16(s_ + 16, d_ + 512 * 8);                                       \
    } while (0)

#define LOAD_A(mq)                                                            \
    {                                                                         \
        const short* At = &lds[t & 3][0][0][0];                               \
        _Pragma("unroll")                                                     \
        for (int m = 0; m < 4; ++m)                                           \
            av[m] = *(const short8*)&At[(fk4 * 256 + wm * 128 + (mq) * 64 +   \
                                         m * 16 + fr) * 8];                   \
    }

#define LOAD_B()                                                              \
    {                                                                         \
        const short* Bt = &lds[t & 3][1][0][0];                               \
        _Pragma("unroll")                                                     \
        for (int n = 0; n < 4; ++n)                                           \
            bv[n] = *(const short8*)&Bt[(fk4 * 256 + wn * 64 + n * 16 + fr) * 8]; \
    }

#define MFMA16(mq)                                                            \
    __builtin_amdgcn_s_setprio(1);                                            \
    _Pragma("unroll")                                                         \
    for (int m = 0; m < 4; ++m)                                               \
        _Pragma("unroll")                                                     \
        for (int n = 0; n < 4; ++n)                                           \
            acc[(mq) * 4 + m][n] = __builtin_amdgcn_mfma_f32_16x16x32_bf16(   \
                av[m], bv[n], acc[(mq) * 4 + m][n], 0, 0, 0);                 \
    __builtin_amdgcn_s_setprio(0);

// ---------------------------------------------------------------------------
// GEMM1: H[slot,:] = gelu( x[token_list[slot],:] @ w1[e]^T + b1[e] )
// M=cnt (<=8192/e), N=4096, K=1024 (NT=32). Grid 32mt x 16nt x 8e = 4096.
// ---------------------------------------------------------------------------
__global__ void __launch_bounds__(512, 2)
gemm1_kernel(const short* __restrict__ xb, const short* __restrict__ w1b,
             const float* __restrict__ b1, const int* __restrict__ offs,
             const int* __restrict__ token_list, short* __restrict__ H) {
    const int nwg = 32 * 16 * E_NUM;
    int sid = xcd_swizzle(blockIdx.x, nwg);
    const int mt = sid & 31;
    const int nt = (sid >> 5) & 15;
    const int e  = sid >> 9;

    const int base = offs[e];
    const int cnt = offs[e + 1] - base;
    if (mt * 256 >= cnt) return;

    __shared__ __align__(16) short lds[4][2][1024][8];  // 128 KiB

    const int tid = threadIdx.x;
    const int wid = tid >> 6, lane = tid & 63;
    const int wm = wid >> 2, wn = wid & 3;
    const int fr = lane & 15, fk4 = lane >> 4;
    const int row_s = tid & 255, half = tid >> 8;

    // gather A-row pointer (one per thread; same row both staged chunks)
    int slotc = min(base + mt * 256 + row_s, base + cnt - 1);
    int tok = token_list[slotc];
    const short* aptr = xb + (size_t)tok * D_DIM + half * 8;
    const short* bptr = w1b + ((size_t)e * F_DIM + nt * 256 + row_s) * D_DIM + half * 8;

    f32x4 acc[8][4];
#pragma unroll
    for (int m = 0; m < 8; ++m)
#pragma unroll
        for (int n = 0; n < 4; ++n) acc[m][n] = (f32x4){0.f, 0.f, 0.f, 0.f};

    const int NT = D_DIM / 32;  // 32
    // prologue: stage tiles 0 and 1
    STAGE(0, aptr, 0); STAGE(1, bptr, 0);
    STAGE(0, aptr, 1); STAGE(1, bptr, 1);
    WAITV4();
    SBAR();
    SCHEDB();

    for (int t = 0; t < NT; ++t) {
        short8 av[4], bv[4];
        // ---- phase 0: quadrant mq=0 ----
        LOAD_A(0); LOAD_B();
        if (t + 2 < NT) STAGE(0, aptr, t + 2);
        SBAR();
        MFMA16(0);
        SBAR();
        // ---- phase 1: quadrant mq=1 ----
        LOAD_A(1);
        if (t + 2 < NT) STAGE(1, bptr, t + 2);
        SBAR();
        MFMA16(1);
        if (t < NT - 1) {
            if (t + 2 < NT) WAITV4(); else WAITV0();
        }
        SBAR();
        SCHEDB();
    }

    // epilogue: bias + exact GELU -> bf16 H
    float bias[4];
#pragma unroll
    for (int n = 0; n < 4; ++n)
        bias[n] = b1[(size_t)e * F_DIM + nt * 256 + wn * 64 + n * 16 + fr];
#pragma unroll
    for (int m = 0; m < 8; ++m) {
        int grow = mt * 256 + wm * 128 + m * 16 + fk4 * 4;
#pragma unroll
        for (int r = 0; r < 4; ++r) {
            if (grow + r < cnt) {
                size_t rowoff = (size_t)(base + grow + r) * F_DIM + nt * 256 + wn * 64 + fr;
#pragma unroll
                for (int n = 0; n < 4; ++n) {
                    float v = acc[m][n][r] + bias[n];
                    v = 0.5f * v * (1.f + erff(v * 0.70710678118654752f));
                    H[rowoff + n * 16] = bf16bits(v);
                }
            }
        }
    }
}

// ---------------------------------------------------------------------------
// GEMM2: out[tok,:] += slot_w * ( H[slot,:] @ w2[e]^T + b2[e] )
// M=cnt, N=1024, K=4096 split in 2 (NT=64 each). Grid 4nt x 32mt x 2ks x 8e.
// ---------------------------------------------------------------------------
__global__ void __launch_bounds__(512, 2)
gemm2_kernel(const short* __restrict__ H, const short* __restrict__ w2b,
             const float* __restrict__ b2, const int* __restrict__ offs,
             const int* __restrict__ token_list, const float* __restrict__ slot_w,
             float* __restrict__ out) {
    const int nwg = 4 * 32 * 2 * E_NUM;
    int sid = xcd_swizzle(blockIdx.x, nwg);
    const int nt = sid & 3;
    const int mt = (sid >> 2) & 31;
    const int ks = (sid >> 7) & 1;
    const int e  = sid >> 8;

    const int base = offs[e];
    const int cnt = offs[e + 1] - base;
    if (mt * 256 >= cnt) return;

    __shared__ __align__(16) short lds[4][2][1024][8];  // 128 KiB

    const int tid = threadIdx.x;
    const int wid = tid >> 6, lane = tid & 63;
    const int wm = wid >> 2, wn = wid & 3;
    const int fr = lane & 15, fk4 = lane >> 4;
    const int row_s = tid & 255, half = tid >> 8;

    int slotc = min(base + mt * 256 + row_s, base + cnt - 1);
    const short* aptr = H + (size_t)slotc * F_DIM + ks * 2048 + half * 8;
    const short* bptr = w2b + ((size_t)e * D_DIM + nt * 256 + row_s) * F_DIM + ks * 2048 + half * 8;

    f32x4 acc[8][4];
#pragma unroll
    for (int m = 0; m < 8; ++m)
#pragma unroll
        for (int n = 0; n < 4; ++n) acc[m][n] = (f32x4){0.f, 0.f, 0.f, 0.f};

    const int NT = 2048 / 32;  // 64
    STAGE(0, aptr, 0); STAGE(1, bptr, 0);
    STAGE(0, aptr, 1); STAGE(1, bptr, 1);
    WAITV4();
    SBAR();
    SCHEDB();

    for (int t = 0; t < NT; ++t) {
        short8 av[4], bv[4];
        LOAD_A(0); LOAD_B();
        if (t + 2 < NT) STAGE(0, aptr, t + 2);
        SBAR();
        MFMA16(0);
        SBAR();
        LOAD_A(1);
        if (t + 2 < NT) STAGE(1, bptr, t + 2);
        SBAR();
        MFMA16(1);
        if (t < NT - 1) {
            if (t + 2 < NT) WAITV4(); else WAITV0();
        }
        SBAR();
        SCHEDB();
    }

    // epilogue: (+bias on ks==0), scale by gate weight, atomic accumulate
    float b2v[4];
#pragma unroll
    for (int n = 0; n < 4; ++n)
        b2v[n] = (ks == 0) ? b2[(size_t)e * D_DIM + nt * 256 + wn * 64 + n * 16 + fr] : 0.f;
#pragma unroll
    for (int m = 0; m < 8; ++m) {
        int grow = mt * 256 + wm * 128 + m * 16 + fk4 * 4;
#pragma unroll
        for (int r = 0; r < 4; ++r) {
            if (grow + r < cnt) {
                int slot = base + grow + r;
                int tok = token_list[slot];
                float w = slot_w[slot];
                float* orow = out + (size_t)tok * D_DIM + nt * 256 + wn * 64 + fr;
#pragma unroll
                for (int n = 0; n < 4; ++n) {
                    atomicAdd(&orow[n * 16], (acc[m][n][r] + b2v[n]) * w);
                }
            }
        }
    }
}

// ---------------------------------------------------------------------------
extern "C" void kernel_launch(void* const* d_in, const int* in_sizes, int n_in,
                              void* d_out, int out_size, void* d_ws, size_t ws_size,
                              hipStream_t stream) {
    const float* x      = (const float*)d_in[0];
    const float* gate_w = (const float*)d_in[1];
    const float* w1     = (const float*)d_in[2];
    const float* b1     = (const float*)d_in[3];
    const float* w2     = (const float*)d_in[4];
    const float* b2     = (const float*)d_in[5];

    float* out   = (float*)d_out;                    // [T, D]
    float* probs = out + (size_t)T_TOK * D_DIM;      // [T, E]

    char* w = (char*)d_ws;
    int* counts = (int*)w;
    int* offs   = (int*)(w + 64);
    size_t off = 256;
    int4*   idxrank    = (int4*)(w + off);  off += (size_t)T_TOK * 16;
    float2* ww_        = (float2*)(w + off); off += (size_t)T_TOK * 8;
    int*    token_list = (int*)(w + off);   off += (size_t)T_TOK * KTOP * 4;
    float*  slot_w     = (float*)(w + off); off += (size_t)T_TOK * KTOP * 4;
    short*  xb  = (short*)(w + off); off += (size_t)T_TOK * D_DIM * 2;
    short*  w1b = (short*)(w + off); off += (size_t)E_NUM * F_DIM * D_DIM * 2;
    short*  w2b = (short*)(w + off); off += (size_t)E_NUM * D_DIM * F_DIM * 2;
    short*  H   = (short*)(w + off); off += (size_t)T_TOK * KTOP * F_DIM * 2;
    (void)ws_size;

    hipMemsetAsync(out, 0, (size_t)T_TOK * D_DIM * sizeof(float), stream);
    hipMemsetAsync(counts, 0, 64, stream);

    cvt_kernel<<<4096, 256, 0, stream>>>(w1, w1b, E_NUM * F_DIM * D_DIM / 8);
    cvt_kernel<<<4096, 256, 0, stream>>>(w2, w2b, E_NUM * D_DIM * F_DIM / 8);

    gate_kernel<<<T_TOK / 4, 256, 0, stream>>>(x, gate_w, probs, idxrank, ww_, counts, xb);
    scan_kernel<<<1, 64, 0, stream>>>(counts, offs);
    scatter_kernel<<<T_TOK / 256, 256, 0, stream>>>(idxrank, ww_, offs, token_list, slot_w);

    gemm1_kernel<<<32 * 16 * E_NUM, 512, 0, stream>>>(
        xb, w1b, b1, offs, token_list, H);
    gemm2_kernel<<<4 * 32 * 2 * E_NUM, 512, 0, stream>>>(
        H, w2b, b2, offs, token_list, slot_w, out);
}